// Round 1
// baseline (277.272 us; speedup 1.0000x reference)
//
#include <hip/hip_runtime.h>

// RWKV chunked wkv recurrence, MI355X (gfx950).
// Shapes: T=32 steps, H=4096 heads, D=64.
// One wave (64 lanes) per head; lane i owns state row S[i][0..63] in VGPRs.
// Per step: k/r staged in LDS, read back as broadcast float4 (conflict-free);
// v/td/tf are lane-local. Sequential T loop (true recurrence; no closed form
// used to avoid cumprod underflow/division numerics).

#define TT 32
#define HH 4096
#define DD 64

__global__ __launch_bounds__(64, 4)
void wkv_chunk_kernel(const float* __restrict__ k,
                      const float* __restrict__ v,
                      const float* __restrict__ r,
                      const float* __restrict__ state_in,
                      const float* __restrict__ td,
                      const float* __restrict__ tf,
                      float* __restrict__ out,        // [T,H,D]
                      float* __restrict__ state_out)  // [H,D,D]
{
    const int h    = blockIdx.x;     // one head per (single-wave) block
    const int lane = threadIdx.x;    // 0..63 = row index i

    __shared__ __align__(16) float lk[DD];
    __shared__ __align__(16) float lr[DD];

    // ---- load state row i into registers (64 VGPRs) ----
    float S[DD];
    {
        const float* sp = state_in + (size_t)(h * DD + lane) * DD;
        #pragma unroll
        for (int jq = 0; jq < DD / 4; ++jq) {
            const float4 s4 = reinterpret_cast<const float4*>(sp)[jq];
            S[4 * jq + 0] = s4.x;
            S[4 * jq + 1] = s4.y;
            S[4 * jq + 2] = s4.z;
            S[4 * jq + 3] = s4.w;
        }
    }

    const float tfi = tf[h * DD + lane];

    for (int t = 0; t < TT; ++t) {
        const int base = (t * HH + h) * DD;
        // coalesced 256B loads; lane index doubles as j (for k,r) and i (for v,td)
        const float kj  = k[base + lane];
        const float rj  = r[base + lane];
        const float vi  = v[base + lane];
        const float tdi = td[base + lane];

        lk[lane] = kj;
        lr[lane] = rj;
        __syncthreads();   // single-wave block: lowers to a wave-level fence

        float acc = 0.0f;
        #pragma unroll
        for (int jq = 0; jq < DD / 4; ++jq) {
            const float4 k4 = reinterpret_cast<const float4*>(lk)[jq];
            const float4 r4 = reinterpret_cast<const float4*>(lr)[jq];
            float kv;
            kv = vi * k4.x;
            acc = fmaf(fmaf(tfi, kv, S[4 * jq + 0]), r4.x, acc);
            S[4 * jq + 0] = fmaf(tdi, S[4 * jq + 0], kv);
            kv = vi * k4.y;
            acc = fmaf(fmaf(tfi, kv, S[4 * jq + 1]), r4.y, acc);
            S[4 * jq + 1] = fmaf(tdi, S[4 * jq + 1], kv);
            kv = vi * k4.z;
            acc = fmaf(fmaf(tfi, kv, S[4 * jq + 2]), r4.z, acc);
            S[4 * jq + 2] = fmaf(tdi, S[4 * jq + 2], kv);
            kv = vi * k4.w;
            acc = fmaf(fmaf(tfi, kv, S[4 * jq + 3]), r4.w, acc);
            S[4 * jq + 3] = fmaf(tdi, S[4 * jq + 3], kv);
        }

        out[base + lane] = acc;
        __syncthreads();   // protect lk/lr before next step's overwrite
    }

    // ---- store final state row ----
    {
        float* sp = state_out + (size_t)(h * DD + lane) * DD;
        #pragma unroll
        for (int jq = 0; jq < DD / 4; ++jq) {
            float4 s4;
            s4.x = S[4 * jq + 0];
            s4.y = S[4 * jq + 1];
            s4.z = S[4 * jq + 2];
            s4.w = S[4 * jq + 3];
            reinterpret_cast<float4*>(sp)[jq] = s4;
        }
    }
}

extern "C" void kernel_launch(void* const* d_in, const int* in_sizes, int n_in,
                              void* d_out, int out_size, void* d_ws, size_t ws_size,
                              hipStream_t stream) {
    const float* k     = (const float*)d_in[0];  // [T,H,1,D]
    const float* v     = (const float*)d_in[1];  // [T,H,D,1]
    const float* r     = (const float*)d_in[2];  // [T,H,D,1]
    const float* state = (const float*)d_in[3];  // [H,D,D]
    const float* td    = (const float*)d_in[4];  // [T,H,D,1]
    const float* tf    = (const float*)d_in[5];  // [H,D,1]

    float* out       = (float*)d_out;                    // [T,H,D] first
    float* state_out = (float*)d_out + (size_t)TT * HH * DD;  // then [H,D,D]

    wkv_chunk_kernel<<<dim3(HH), dim3(64), 0, stream>>>(
        k, v, r, state, td, tf, out, state_out);
}